// Round 1
// baseline (79.193 us; speedup 1.0000x reference)
//
#include <hip/hip_runtime.h>
#include <hip/hip_bf16.h>

// Problem: B=4, T=256, U=65, D=512, V=1024, fp32.
// out[b,t,u,v] = encP[b,t,v] + decP[b,u,v]
//   encP = gelu_tanh(enc) @ W[:, :D]^T   (M=1024, N=1024, K=512)
//   decP = gelu_tanh(dec) @ W[:, D:]^T   (M=260,  N=1024, K=512)

#define B_ 4
#define T_ 256
#define U_ 65
#define D_ 512
#define V_ 1024

typedef __attribute__((ext_vector_type(8))) short bf16x8;   // 8 bf16 = 4 VGPRs
typedef __attribute__((ext_vector_type(4))) float f32x4;

__device__ __forceinline__ float gelu_tanh(float x) {
    const float c = 0.7978845608028654f;  // sqrt(2/pi)
    float x3 = x * x * x;
    float t = tanhf(c * (x + 0.044715f * x3));
    return 0.5f * x * (1.0f + t);
}

// ---------------------------------------------------------------------------
// Kernel 1: gelu+cast enc/dec to bf16, cast W to bf16. float4-vectorized.
// ---------------------------------------------------------------------------
__global__ __launch_bounds__(256)
void prep_kernel(const float* __restrict__ enc,
                 const float* __restrict__ dec,
                 const float* __restrict__ W,
                 __hip_bfloat16* __restrict__ geB,
                 __hip_bfloat16* __restrict__ gdB,
                 __hip_bfloat16* __restrict__ WB) {
    const int NE4 = (B_ * T_ * D_) / 4;     // 131072
    const int ND4 = (B_ * U_ * D_) / 4;     // 33280
    const int NW4 = (V_ * 2 * D_) / 4;      // 262144
    int i = blockIdx.x * blockDim.x + threadIdx.x;
    if (i < NE4) {
        float4 v = ((const float4*)enc)[i];
        __hip_bfloat16* p = geB + i * 4;
        p[0] = __float2bfloat16(gelu_tanh(v.x));
        p[1] = __float2bfloat16(gelu_tanh(v.y));
        p[2] = __float2bfloat16(gelu_tanh(v.z));
        p[3] = __float2bfloat16(gelu_tanh(v.w));
    } else if (i < NE4 + ND4) {
        int j = i - NE4;
        float4 v = ((const float4*)dec)[j];
        __hip_bfloat16* p = gdB + j * 4;
        p[0] = __float2bfloat16(gelu_tanh(v.x));
        p[1] = __float2bfloat16(gelu_tanh(v.y));
        p[2] = __float2bfloat16(gelu_tanh(v.z));
        p[3] = __float2bfloat16(gelu_tanh(v.w));
    } else if (i < NE4 + ND4 + NW4) {
        int j = i - NE4 - ND4;
        float4 v = ((const float4*)W)[j];
        __hip_bfloat16* p = WB + j * 4;
        p[0] = __float2bfloat16(v.x);
        p[1] = __float2bfloat16(v.y);
        p[2] = __float2bfloat16(v.z);
        p[3] = __float2bfloat16(v.w);
    }
}

// ---------------------------------------------------------------------------
// Kernel 2: bf16 MFMA GEMM, NT layout (both operands K-contiguous).
// 64x64 tile per 256-thread block; 4 waves in 2x2; each wave 2x2 of 16x16 frags.
// No LDS: operands are small (ge 1MB, W 2MB bf16) -> L2-resident direct loads.
// Blocks 0..255: enc (16 Mtiles x 16 Ntiles). Blocks 256..335: dec (5 x 16).
// ---------------------------------------------------------------------------
__global__ __launch_bounds__(256)
void gemm_kernel(const __hip_bfloat16* __restrict__ geB,
                 const __hip_bfloat16* __restrict__ gdB,
                 const __hip_bfloat16* __restrict__ WB,
                 float* __restrict__ encP,
                 float* __restrict__ decP) {
    int blk = blockIdx.x;
    const __hip_bfloat16* A;
    float* C;
    int M, kofs, mt, nt;
    if (blk < 256) {
        A = geB; C = encP; M = B_ * T_; kofs = 0;
        mt = blk >> 4; nt = blk & 15;
    } else {
        blk -= 256;
        A = gdB; C = decP; M = B_ * U_; kofs = D_;
        mt = blk >> 4; nt = blk & 15;
    }
    const int lane = threadIdx.x & 63;
    const int w    = threadIdx.x >> 6;     // 0..3
    const int wr   = w >> 1, wc = w & 1;   // waves 2x2 over the 64x64 tile
    const int r16  = lane & 15;            // A row / B col within fragment
    const int k8   = (lane >> 4) * 8;      // K sub-offset within K=32 step

    const int m_base = mt * 64 + wr * 32;
    const int n_base = nt * 64 + wc * 32;

    f32x4 acc[2][2] = {};
    for (int k0 = 0; k0 < D_; k0 += 32) {
        bf16x8 a[2], b[2];
#pragma unroll
        for (int mi = 0; mi < 2; ++mi) {
            int row = m_base + mi * 16 + r16;
            int rr = row < M ? row : 0;    // clamp (stores are guarded)
            a[mi] = *(const bf16x8*)(A + (size_t)rr * D_ + k0 + k8);
        }
#pragma unroll
        for (int ni = 0; ni < 2; ++ni) {
            int col = n_base + ni * 16 + r16;
            b[ni] = *(const bf16x8*)(WB + (size_t)col * (2 * D_) + kofs + k0 + k8);
        }
#pragma unroll
        for (int mi = 0; mi < 2; ++mi)
#pragma unroll
            for (int ni = 0; ni < 2; ++ni)
                acc[mi][ni] = __builtin_amdgcn_mfma_f32_16x16x32_bf16(
                    a[mi], b[ni], acc[mi][ni], 0, 0, 0);
    }
    // C/D layout: col = lane&15, row = (lane>>4)*4 + j   [guide §3, m89-verified]
    const int c_row0 = (lane >> 4) * 4;
#pragma unroll
    for (int mi = 0; mi < 2; ++mi) {
#pragma unroll
        for (int j = 0; j < 4; ++j) {
            int row = m_base + mi * 16 + c_row0 + j;
            if (row < M) {
#pragma unroll
                for (int ni = 0; ni < 2; ++ni) {
                    int col = n_base + ni * 16 + r16;
                    C[(size_t)row * V_ + col] = acc[mi][ni][j];
                }
            }
        }
    }
}

// ---------------------------------------------------------------------------
// Kernel 3: broadcast add, float4-vectorized, grid-stride over (b,t,u) rows.
// Write-bound: 272.6 MB out. enc/dec rows are L2-resident (5 MB total).
// ---------------------------------------------------------------------------
__global__ __launch_bounds__(256)
void bcast_kernel(const float* __restrict__ encP,
                  const float* __restrict__ decP,
                  float* __restrict__ out) {
    const int NROWS = B_ * T_ * U_;        // 66560
    const int tid = threadIdx.x;           // 256 threads * float4 = V=1024
    for (int n = blockIdx.x; n < NROWS; n += gridDim.x) {
        int bt = n / U_;
        int u  = n - bt * U_;
        int b  = bt >> 8;                  // T_ = 256
        const float4* e4 = (const float4*)(encP + (size_t)bt * V_);
        const float4* d4 = (const float4*)(decP + ((size_t)b * U_ + u) * V_);
        float4* o4 = (float4*)(out + (size_t)n * V_);
        float4 ev = e4[tid];
        float4 dv = d4[tid];
        float4 ov;
        ov.x = ev.x + dv.x;
        ov.y = ev.y + dv.y;
        ov.z = ev.z + dv.z;
        ov.w = ev.w + dv.w;
        o4[tid] = ov;
    }
}

extern "C" void kernel_launch(void* const* d_in, const int* in_sizes, int n_in,
                              void* d_out, int out_size, void* d_ws, size_t ws_size,
                              hipStream_t stream) {
    const float* enc = (const float*)d_in[0];   // (4,256,512)
    const float* dec = (const float*)d_in[1];   // (4,65,512)
    const float* W   = (const float*)d_in[2];   // (1024, 1024)
    float* out = (float*)d_out;                 // (4,256,65,1024)

    char* ws = (char*)d_ws;
    // workspace layout (needs ~8.6 MB):
    __hip_bfloat16* geB  = (__hip_bfloat16*)(ws);              // 1.00 MB
    __hip_bfloat16* gdB  = (__hip_bfloat16*)(ws + 0x100000);   // 0.26 MB
    __hip_bfloat16* WB   = (__hip_bfloat16*)(ws + 0x180000);   // 2.00 MB
    float*          encP = (float*)(ws + 0x380000);            // 4.00 MB
    float*          decP = (float*)(ws + 0x780000);            // 1.04 MB

    const int total4 = (B_ * T_ * D_ + B_ * U_ * D_ + V_ * 2 * D_) / 4;  // 426496
    prep_kernel<<<(total4 + 255) / 256, 256, 0, stream>>>(enc, dec, W, geB, gdB, WB);
    gemm_kernel<<<256 + 80, 256, 0, stream>>>(geB, gdB, WB, encP, decP);
    bcast_kernel<<<2048, 256, 0, stream>>>(encP, decP, out);
}